// Round 1
// baseline (786.387 us; speedup 1.0000x reference)
//
#include <hip/hip_runtime.h>

// FGIAN BiLSTM+attention. Pipeline:
//   k_lens -> k_prep_emb/k_prep_w (f32->bf16, K padded 300->320)
//   k_gemm (bf16 MFMA 16x16x32, gathered-A, xproj = emb[idx] @ Wih_cat^T + b)
//   memset(M) -> k_scan (512 concurrent masked-LSTM scans, Whh in VGPRs)
//   k_rowdot (a_t, b_p) -> k_align (m_t + col partial max) -> k_colmax
//   k_feat (softmax + weighted sums) -> k_out (feat @ Wd^T + bd)
// Workspace: ~252 MB with phase overlays (stream order makes them safe).

#define B 128
#define TBODY 512
#define TPUN 256
#define EMB 300
#define EMBP 320
#define VOCAB 50000
#define HID 64
#define G4 256
#define NG 512
#define DM 128

typedef __attribute__((ext_vector_type(8))) short bf16x8;
typedef __attribute__((ext_vector_type(4))) float floatx4;
typedef unsigned short u16;

// ---- workspace layout (bytes) ----
#define OFF_XPB   0u                    // f32 [B*TBODY*NG] = 134217728
#define OFF_XPP   134217728u            // f32 [B*TPUN*NG]  =  67108864
#define OFF_BODYM 201326592u            // f32 [B*TBODY*DM] =  33554432
#define OFF_PUNM  234881024u            // f32 [B*TPUN*DM]  =  16777216
#define OFF_SMALL 251658240u
// overlays in xpB (dead after k_scan):
#define OFF_ABODY (OFF_XPB + 0u)        // 262144
#define OFF_APUN  (OFF_XPB + 262144u)   // 131072
#define OFF_MT    (OFF_XPB + 393216u)   // 262144
#define OFF_MP    (OFF_XPB + 655360u)   // 131072
#define OFF_COLP  (OFF_XPB + 786432u)   // 1048576
// overlays in bodyM/punM (dead until memset AFTER gemms):
#define OFF_EMBB  OFF_BODYM             // bf16 [VOCAB*EMBP] = 32000000
#define OFF_WCB   OFF_PUNM              // bf16 [NG*EMBP] = 327680
#define OFF_WCP   (OFF_PUNM + 327680u)
#define OFF_BIASB (OFF_PUNM + 655360u)  // 2048
#define OFF_BIASP (OFF_PUNM + 657408u)
#define OFF_LENS  OFF_SMALL             // 1024
#define OFF_FEAT  (OFF_SMALL + 1024u)   // 131072

__device__ inline u16 f2bf(float v) {
    unsigned int u = __float_as_uint(v);
    unsigned int r = (u + 0x7FFFu + ((u >> 16) & 1u)) >> 16;  // RNE
    return (u16)r;
}

// ---------------- lens ----------------
__global__ __launch_bounds__(256) void k_lens(const int* __restrict__ bidx,
                                              const int* __restrict__ pidx,
                                              int* __restrict__ lens) {
    int j = blockIdx.x, tid = threadIdx.x;
    const int* src; int n;
    if (j < B) { src = bidx + (size_t)j * TBODY; n = TBODY; }
    else       { src = pidx + (size_t)(j - B) * TPUN; n = TPUN; }
    int c = 0;
    for (int t = tid; t < n; t += 256) c += (src[t] != 0) ? 1 : 0;
    for (int o = 32; o; o >>= 1) c += __shfl_xor(c, o, 64);
    __shared__ int red[4];
    if ((tid & 63) == 0) red[tid >> 6] = c;
    __syncthreads();
    if (tid == 0) lens[j] = red[0] + red[1] + red[2] + red[3];
}

// ---------------- prep: emb -> bf16 padded ----------------
__global__ __launch_bounds__(256) void k_prep_emb(const float* __restrict__ emb,
                                                  u16* __restrict__ embb) {
    int e = blockIdx.x * 256 + threadIdx.x;  // exactly VOCAB*EMBP
    int row = e / EMBP, d = e - row * EMBP;
    float v = (d < EMB) ? emb[(size_t)row * EMB + d] : 0.f;
    embb[e] = f2bf(v);
}

// ---------------- prep: weights concat f/b -> bf16 padded + biases ----------------
__global__ __launch_bounds__(256) void k_prep_w(
    const float* __restrict__ bWih_f, const float* __restrict__ bWih_b,
    const float* __restrict__ bb_f, const float* __restrict__ bb_b,
    const float* __restrict__ pWih_f, const float* __restrict__ pWih_b,
    const float* __restrict__ pb_f, const float* __restrict__ pb_b,
    u16* __restrict__ Wcb, u16* __restrict__ Wcp,
    float* __restrict__ biasb, float* __restrict__ biasp) {
    int e = blockIdx.x * 256 + threadIdx.x;
    const int WSZ = NG * EMBP;  // 163840
    if (e < WSZ) {
        int g = e / EMBP, d = e - g * EMBP;
        float v = 0.f;
        if (d < EMB) v = (g < G4) ? bWih_f[g * EMB + d] : bWih_b[(g - G4) * EMB + d];
        Wcb[e] = f2bf(v);
    } else if (e < 2 * WSZ) {
        int ee = e - WSZ;
        int g = ee / EMBP, d = ee - g * EMBP;
        float v = 0.f;
        if (d < EMB) v = (g < G4) ? pWih_f[g * EMB + d] : pWih_b[(g - G4) * EMB + d];
        Wcp[ee] = f2bf(v);
    } else if (e < 2 * WSZ + NG) {
        int g = e - 2 * WSZ;
        biasb[g] = (g < G4) ? bb_f[g] : bb_b[g - G4];
    } else if (e < 2 * WSZ + 2 * NG) {
        int g = e - 2 * WSZ - NG;
        biasp[g] = (g < G4) ? pb_f[g] : pb_b[g - G4];
    }
}

// ---------------- bf16 MFMA GEMM: out[m,g] = sum_k embb[idx[m],k]*Wc[g,k] + bias[g] ----------------
__global__ __launch_bounds__(256) void k_gemm(const int* __restrict__ idx,
                                              const u16* __restrict__ embb,
                                              const u16* __restrict__ Wc,
                                              const float* __restrict__ biasc,
                                              float* __restrict__ out) {
    __shared__ u16 As[64 * 40];  // row stride 40 (80B) -> even bank spread
    __shared__ u16 Bs[64 * 40];
    int tid = threadIdx.x;
    int m0 = blockIdx.x * 64;
    int g0 = blockIdx.y * 64;
    int wave = tid >> 6, lane = tid & 63;
    int r = tid >> 2, seg = tid & 3;
    int arow = idx[m0 + r];
    const u16* aptr = embb + (size_t)arow * EMBP + seg * 8;
    const u16* bptr = Wc + (size_t)(g0 + r) * EMBP + seg * 8;
    u16* asd = As + r * 40 + seg * 8;
    u16* bsd = Bs + r * 40 + seg * 8;
    floatx4 acc0 = {0.f, 0.f, 0.f, 0.f}, acc1 = acc0, acc2 = acc0, acc3 = acc0;
    int l15 = lane & 15, quad = lane >> 4;
    int row = wave * 16 + l15;
    for (int k0 = 0; k0 < EMBP; k0 += 32) {
        uint4 av = *(const uint4*)(aptr + k0);
        uint4 bv = *(const uint4*)(bptr + k0);
        *(uint4*)asd = av;
        *(uint4*)bsd = bv;
        __syncthreads();
        bf16x8 a  = *(const bf16x8*)(As + row * 40 + quad * 8);
        bf16x8 b0 = *(const bf16x8*)(Bs + (l15)*40 + quad * 8);
        bf16x8 b1 = *(const bf16x8*)(Bs + (16 + l15) * 40 + quad * 8);
        bf16x8 b2 = *(const bf16x8*)(Bs + (32 + l15) * 40 + quad * 8);
        bf16x8 b3 = *(const bf16x8*)(Bs + (48 + l15) * 40 + quad * 8);
        acc0 = __builtin_amdgcn_mfma_f32_16x16x32_bf16(a, b0, acc0, 0, 0, 0);
        acc1 = __builtin_amdgcn_mfma_f32_16x16x32_bf16(a, b1, acc1, 0, 0, 0);
        acc2 = __builtin_amdgcn_mfma_f32_16x16x32_bf16(a, b2, acc2, 0, 0, 0);
        acc3 = __builtin_amdgcn_mfma_f32_16x16x32_bf16(a, b3, acc3, 0, 0, 0);
        __syncthreads();
    }
    float bias0 = biasc[g0 + l15], bias1 = biasc[g0 + 16 + l15];
    float bias2 = biasc[g0 + 32 + l15], bias3 = biasc[g0 + 48 + l15];
    int mbase = m0 + wave * 16 + quad * 4;
#pragma unroll
    for (int rg = 0; rg < 4; rg++) {
        size_t ro = (size_t)(mbase + rg) * NG + g0;
        out[ro + l15] = acc0[rg] + bias0;
        out[ro + 16 + l15] = acc1[rg] + bias1;
        out[ro + 32 + l15] = acc2[rg] + bias2;
        out[ro + 48 + l15] = acc3[rg] + bias3;
    }
}

// ---------------- masked LSTM scans: 512 independent blocks ----------------
__global__ __launch_bounds__(256) void k_scan(
    const float* __restrict__ xpB, const float* __restrict__ xpP,
    float* __restrict__ bodyM, float* __restrict__ punM,
    const int* __restrict__ lens,
    const float* __restrict__ bWhh_f, const float* __restrict__ bWhh_b,
    const float* __restrict__ pWhh_f, const float* __restrict__ pWhh_b) {
    int task = blockIdx.x, tid = threadIdx.x;
    int isPun = task >> 8;
    int sub = task & 255;
    int b = sub & 127, dir = sub >> 7;
    int T = isPun ? TPUN : TBODY;
    int len = lens[(isPun ? B : 0) + b];
    const float* xp = (isPun ? xpP : xpB) + (size_t)b * T * NG + dir * G4;
    float* outp = (isPun ? punM : bodyM) + (size_t)b * T * DM + dir * HID;
    const float* Whh = isPun ? (dir ? pWhh_b : pWhh_f) : (dir ? bWhh_b : bWhh_f);
    // gate row j=tid of Whh in registers
    float w[64];
    const float4* wr = (const float4*)(Whh + tid * 64);
#pragma unroll
    for (int k = 0; k < 16; k++) {
        float4 t4 = wr[k];
        w[4 * k] = t4.x; w[4 * k + 1] = t4.y; w[4 * k + 2] = t4.z; w[4 * k + 3] = t4.w;
    }
    __shared__ __align__(16) float h_lds[64];
    __shared__ __align__(16) float c_lds[64];
    __shared__ float g_lds[256];
    if (tid < 64) { h_lds[tid] = 0.f; c_lds[tid] = 0.f; }
    __syncthreads();
    if (len <= 0) return;
    float xv_next = xp[(size_t)(dir ? (len - 1) : 0) * NG + tid];
    for (int s = 0; s < len; ++s) {
        int p = dir ? (len - 1 - s) : s;
        float xv = xv_next;
        if (s + 1 < len) {
            int pn = dir ? (len - 2 - s) : (s + 1);
            xv_next = xp[(size_t)pn * NG + tid];  // prefetch next step
        }
        float sum = 0.f;
#pragma unroll
        for (int k4 = 0; k4 < 16; k4++) {
            float4 hv = ((const float4*)h_lds)[k4];
            sum += hv.x * w[4 * k4] + hv.y * w[4 * k4 + 1] + hv.z * w[4 * k4 + 2] + hv.w * w[4 * k4 + 3];
        }
        float pre = xv + sum;
        float val;
        if ((tid >> 6) == 2) val = tanhf(pre);          // g-gate
        else val = 1.f / (1.f + __expf(-pre));          // i,f,o
        g_lds[tid] = val;
        __syncthreads();
        if (tid < 64) {
            float ig = g_lds[tid], fg = g_lds[64 + tid], gg = g_lds[128 + tid], og = g_lds[192 + tid];
            float cn = fg * c_lds[tid] + ig * gg;
            float hn = og * tanhf(cn);
            c_lds[tid] = cn; h_lds[tid] = hn;
            outp[(size_t)p * DM + tid] = hn;
        }
        __syncthreads();
    }
}

// ---------------- a_t = body_M.w1, b_p = pun_M.w2 (one wave per row) ----------------
__global__ __launch_bounds__(256) void k_rowdot(const float* __restrict__ bodyM,
                                                const float* __restrict__ punM,
                                                const float* __restrict__ w_u,
                                                float* __restrict__ a_body,
                                                float* __restrict__ a_pun) {
    int wid = (blockIdx.x * 256 + threadIdx.x) >> 6;
    int lane = threadIdx.x & 63;
    const int NB = B * TBODY;
    const float* src; const float* wv; float* dst;
    if (wid < NB) { src = bodyM + (size_t)wid * DM; wv = w_u; dst = a_body + wid; }
    else { src = punM + (size_t)(wid - NB) * DM; wv = w_u + DM; dst = a_pun + (wid - NB); }
    float2 v = ((const float2*)src)[lane];
    float2 w = ((const float2*)wv)[lane];
    float s = v.x * w.x + v.y * w.y;
    for (int o = 32; o; o >>= 1) s += __shfl_xor(s, o, 64);
    if (lane == 0) *dst = s;
}

// ---------------- align tile: m_t (full) + col partial maxes ----------------
__global__ __launch_bounds__(256) void k_align(
    const float* __restrict__ bodyM, const float* __restrict__ punM,
    const float* __restrict__ a_body, const float* __restrict__ a_pun,
    const float* __restrict__ w_u,
    float* __restrict__ m_t, float* __restrict__ colpart) {
    __shared__ float bw[64 * 132];      // body * w3, stride 132 (b128-aligned, broadcast reads)
    __shared__ float pu[64 * 129];      // pun raw, stride 129 -> 2-way scalar reads
    __shared__ float colred[64 * 16];
    int tid = threadIdx.x;
    int tt = blockIdx.x, b = blockIdx.y;
    int t0 = tt * 64;
    int ti = tid >> 4, pi = tid & 15;
    const float* w3 = w_u + 2 * DM;
    const float* bsrc = bodyM + ((size_t)b * TBODY + t0) * DM;
#pragma unroll
    for (int j = 0; j < 8; j++) {
        int e = tid + 256 * j;
        int i = e >> 5, c4 = e & 31;
        float4 v = *(const float4*)(bsrc + i * DM + c4 * 4);
        float4 wv = *(const float4*)(w3 + c4 * 4);
        v.x *= wv.x; v.y *= wv.y; v.z *= wv.z; v.w *= wv.w;
        *(float4*)(bw + i * 132 + c4 * 4) = v;
    }
    float aB[4];
#pragma unroll
    for (int a = 0; a < 4; a++) aB[a] = a_body[(size_t)b * TBODY + t0 + ti * 4 + a];
    float mrun[4] = {-1e30f, -1e30f, -1e30f, -1e30f};
    for (int pc = 0; pc < 4; pc++) {
        __syncthreads();
        const float* psrc = punM + ((size_t)b * TPUN + pc * 64) * DM;
#pragma unroll
        for (int j = 0; j < 8; j++) {
            int e = tid + 256 * j;
            int i = e >> 5, c4 = e & 31;
            float4 v = *(const float4*)(psrc + i * DM + c4 * 4);
            pu[i * 129 + c4 * 4 + 0] = v.x;
            pu[i * 129 + c4 * 4 + 1] = v.y;
            pu[i * 129 + c4 * 4 + 2] = v.z;
            pu[i * 129 + c4 * 4 + 3] = v.w;
        }
        __syncthreads();
        float aP[4];
#pragma unroll
        for (int c = 0; c < 4; c++) aP[c] = a_pun[(size_t)b * TPUN + pc * 64 + pi * 4 + c];
        float C[4][4];
#pragma unroll
        for (int a = 0; a < 4; a++)
#pragma unroll
            for (int c = 0; c < 4; c++) C[a][c] = 0.f;
        for (int d4 = 0; d4 < 32; d4++) {
            float4 bq[4];
#pragma unroll
            for (int a = 0; a < 4; a++) bq[a] = *(const float4*)(bw + (ti * 4 + a) * 132 + d4 * 4);
#pragma unroll
            for (int dd = 0; dd < 4; dd++) {
                float pv[4];
#pragma unroll
                for (int c = 0; c < 4; c++) pv[c] = pu[(pi * 4 + c) * 129 + d4 * 4 + dd];
#pragma unroll
                for (int a = 0; a < 4; a++) {
                    float bvv = (dd == 0) ? bq[a].x : (dd == 1) ? bq[a].y : (dd == 2) ? bq[a].z : bq[a].w;
#pragma unroll
                    for (int c = 0; c < 4; c++) C[a][c] += bvv * pv[c];
                }
            }
        }
        float colv[4] = {-1e30f, -1e30f, -1e30f, -1e30f};
#pragma unroll
        for (int a = 0; a < 4; a++) {
            float rm = -1e30f;
#pragma unroll
            for (int c = 0; c < 4; c++) {
                float valv = C[a][c] + aB[a] + aP[c];
                rm = fmaxf(rm, valv);
                colv[c] = fmaxf(colv[c], valv);
            }
#pragma unroll
            for (int o = 1; o < 16; o <<= 1) rm = fmaxf(rm, __shfl_xor(rm, o, 64));
            mrun[a] = fmaxf(mrun[a], rm);
        }
#pragma unroll
        for (int c = 0; c < 4; c++) colred[(pi * 4 + c) * 16 + ti] = colv[c];
        __syncthreads();
        if (tid < 64) {
            float m = -1e30f;
#pragma unroll
            for (int k = 0; k < 16; k++) m = fmaxf(m, colred[tid * 16 + k]);
            colpart[((size_t)b * 8 + tt) * TPUN + pc * 64 + tid] = m;
        }
    }
    if (pi == 0) {
#pragma unroll
        for (int a = 0; a < 4; a++) m_t[(size_t)b * TBODY + t0 + ti * 4 + a] = mrun[a];
    }
}

__global__ __launch_bounds__(256) void k_colmax(const float* __restrict__ colpart,
                                                float* __restrict__ m_p) {
    int b = blockIdx.x, p = threadIdx.x;
    float m = -1e30f;
    for (int tt = 0; tt < 8; tt++) m = fmaxf(m, colpart[((size_t)b * 8 + tt) * TPUN + p]);
    m_p[(size_t)b * TPUN + p] = m;
}

// ---------------- softmax + attention-weighted feature sums ----------------
__global__ __launch_bounds__(256) void k_feat(const float* __restrict__ bodyM,
                                              const float* __restrict__ punM,
                                              const float* __restrict__ m_t,
                                              const float* __restrict__ m_p,
                                              float* __restrict__ feat) {
    int bidx = blockIdx.x;
    int b = bidx & (B - 1), which = bidx >> 7;
    int n = which ? TPUN : TBODY;
    const float* sc = which ? (m_p + (size_t)b * TPUN) : (m_t + (size_t)b * TBODY);
    const float* src = which ? (punM + (size_t)b * TPUN * DM) : (bodyM + (size_t)b * TBODY * DM);
    float* dst = feat + (size_t)b * 256 + which * DM;
    int tid = threadIdx.x;
    __shared__ float e_lds[TBODY];
    __shared__ float red[8];
    __shared__ float red2[256];
    float mx = -1e30f;
    for (int t = tid; t < n; t += 256) mx = fmaxf(mx, sc[t]);
    for (int o = 32; o; o >>= 1) mx = fmaxf(mx, __shfl_xor(mx, o, 64));
    if ((tid & 63) == 0) red[tid >> 6] = mx;
    __syncthreads();
    mx = fmaxf(fmaxf(red[0], red[1]), fmaxf(red[2], red[3]));
    float se = 0.f;
    for (int t = tid; t < n; t += 256) {
        float ev = __expf(sc[t] - mx);
        e_lds[t] = ev;
        se += ev;
    }
    for (int o = 32; o; o >>= 1) se += __shfl_xor(se, o, 64);
    if ((tid & 63) == 0) red[4 + (tid >> 6)] = se;
    __syncthreads();
    se = red[4] + red[5] + red[6] + red[7];
    float inv = 1.f / se;
    int d = tid & 127, half = tid >> 7;
    float acc = 0.f;
    for (int t = half; t < n; t += 2) acc += e_lds[t] * src[(size_t)t * DM + d];
    red2[tid] = acc;
    __syncthreads();
    if (tid < DM) dst[tid] = (red2[tid] + red2[tid + 128]) * inv;
}

// ---------------- out = feat @ Wd^T + bd ----------------
__global__ __launch_bounds__(256) void k_out(const float* __restrict__ feat,
                                             const float* __restrict__ Wd,
                                             const float* __restrict__ bd,
                                             float* __restrict__ outp) {
    int b = blockIdx.x, tid = threadIdx.x;
    float v = feat[(size_t)b * 256 + tid];
    __shared__ float red[12];
#pragma unroll
    for (int pol = 0; pol < 3; pol++) {
        float s = v * Wd[pol * 256 + tid];
        for (int o = 32; o; o >>= 1) s += __shfl_xor(s, o, 64);
        if ((tid & 63) == 0) red[pol * 4 + (tid >> 6)] = s;
    }
    __syncthreads();
    if (tid < 3) outp[b * 3 + tid] = red[tid * 4] + red[tid * 4 + 1] + red[tid * 4 + 2] + red[tid * 4 + 3] + bd[tid];
}

extern "C" void kernel_launch(void* const* d_in, const int* in_sizes, int n_in,
                              void* d_out, int out_size, void* d_ws, size_t ws_size,
                              hipStream_t stream) {
    const int* body_idx = (const int*)d_in[0];
    const int* pun_idx  = (const int*)d_in[1];
    const float* emb    = (const float*)d_in[2];
    const float* w_u    = (const float*)d_in[3];
    const float* Wd     = (const float*)d_in[4];
    const float* bd     = (const float*)d_in[5];
    const float* bWih_f = (const float*)d_in[6];
    const float* bWhh_f = (const float*)d_in[7];
    const float* bb_f   = (const float*)d_in[8];
    const float* bWih_b = (const float*)d_in[9];
    const float* bWhh_b = (const float*)d_in[10];
    const float* bb_b   = (const float*)d_in[11];
    const float* pWih_f = (const float*)d_in[12];
    const float* pWhh_f = (const float*)d_in[13];
    const float* pb_f   = (const float*)d_in[14];
    const float* pWih_b = (const float*)d_in[15];
    const float* pWhh_b = (const float*)d_in[16];
    const float* pb_b   = (const float*)d_in[17];

    char* ws = (char*)d_ws;
    float* xpB   = (float*)(ws + OFF_XPB);
    float* xpP   = (float*)(ws + OFF_XPP);
    float* bodyM = (float*)(ws + OFF_BODYM);
    float* punM  = (float*)(ws + OFF_PUNM);
    u16* embb    = (u16*)(ws + OFF_EMBB);
    u16* Wcb     = (u16*)(ws + OFF_WCB);
    u16* Wcp     = (u16*)(ws + OFF_WCP);
    float* biasb = (float*)(ws + OFF_BIASB);
    float* biasp = (float*)(ws + OFF_BIASP);
    int* lens    = (int*)(ws + OFF_LENS);
    float* a_body = (float*)(ws + OFF_ABODY);
    float* a_pun  = (float*)(ws + OFF_APUN);
    float* m_t    = (float*)(ws + OFF_MT);
    float* m_p    = (float*)(ws + OFF_MP);
    float* colpart = (float*)(ws + OFF_COLP);
    float* feat   = (float*)(ws + OFF_FEAT);
    float* outp   = (float*)d_out;

    k_lens<<<dim3(256), dim3(256), 0, stream>>>(body_idx, pun_idx, lens);
    k_prep_emb<<<dim3(62500), dim3(256), 0, stream>>>(emb, embb);
    k_prep_w<<<dim3(1284), dim3(256), 0, stream>>>(bWih_f, bWih_b, bb_f, bb_b,
                                                   pWih_f, pWih_b, pb_f, pb_b,
                                                   Wcb, Wcp, biasb, biasp);
    k_gemm<<<dim3(1024, 8), dim3(256), 0, stream>>>(body_idx, embb, Wcb, biasb, xpB);
    k_gemm<<<dim3(512, 8), dim3(256), 0, stream>>>(pun_idx, embb, Wcp, biasp, xpP);
    hipMemsetAsync(ws + OFF_BODYM, 0, (size_t)(33554432u + 16777216u), stream);
    k_scan<<<dim3(512), dim3(256), 0, stream>>>(xpB, xpP, bodyM, punM, lens,
                                                bWhh_f, bWhh_b, pWhh_f, pWhh_b);
    k_rowdot<<<dim3(24576), dim3(256), 0, stream>>>(bodyM, punM, w_u, a_body, a_pun);
    k_align<<<dim3(8, 128), dim3(256), 0, stream>>>(bodyM, punM, a_body, a_pun, w_u, m_t, colpart);
    k_colmax<<<dim3(128), dim3(256), 0, stream>>>(colpart, m_p);
    k_feat<<<dim3(256), dim3(256), 0, stream>>>(bodyM, punM, m_t, m_p, feat);
    k_out<<<dim3(128), dim3(256), 0, stream>>>(feat, Wd, bd, outp);
}